// Round 1
// baseline (427.970 us; speedup 1.0000x reference)
//
#include <hip/hip_runtime.h>

// db4 DWT, one level, symmetric padding.
//   cA[t] = sum_m DEC_LO[7-m] * x_sym(2t-6+m),  t in [0, 8195)
//   x_sym(s) = x[-s-1] (s<0), x[s] (0<=s<N), x[2N-1-s] (s>=N)
// out row layout: [cA (8195) | cD (8195)]
//
// R0 changes vs 424-µs baseline:
//  - 512-thread blocks, 2048 outputs/block (grid 4x4096): same 32 waves/CU
//    (34.2 KB LDS -> 4 blocks/CU x 8 waves), half the syncs / border refetch.
//  - non-temporal global loads (x) and stores (out): pure 537 MB stream with
//    zero reuse -> skip cache allocation.
// Structure otherwise identical: LDS stage with +4/32 pad, 4 outputs/thread,
// LDS restage of cA/cD, aligned float4 stores with scalar head/tail.

#define BB      4096
#define NN      16384
#define NOUT    8195
#define OUTROW  16390
#define TOUT_BLK 2048
#define GRIDX   4
#define NTHREADS 512
#define SPAN_ALLOC 4120            // staged floats per block (mult of 4)
#define NLOAD4  (SPAN_ALLOC / 4)   // 1030
#define LDS_IN_SZ 4632             // ldsidx(4116)+4
#define CAP     2056               // >= 2052 outputs staged (last block)

typedef float f4v __attribute__((ext_vector_type(4)));
typedef float f2v __attribute__((ext_vector_type(2)));

__device__ __forceinline__ int ldsidx(int o) { return o + ((o >> 5) << 2); }

__global__ __launch_bounds__(NTHREADS) void WaveletTransform_23244363006050_kernel(
        const float* __restrict__ x, float* __restrict__ out) {
    __shared__ float in_s[LDS_IN_SZ];
    __shared__ float cA_s[CAP];
    __shared__ float cD_s[CAP];

    const int tid = threadIdx.x;
    const int bx  = blockIdx.x;
    const int b   = blockIdx.y;
    const int t0  = bx * TOUT_BLK;
    const int touts = (bx == GRIDX - 1) ? (NOUT - t0) : TOUT_BLK;  // 2048 or 2051
    const float* __restrict__ xr = x + (size_t)b * NN;
    const int s_lo = 2 * t0 - 8;   // first staged input index (16B aligned)

    // ---- Phase 1: global -> LDS (non-temporal float4 loads) ----
    for (int k = tid; k < NLOAD4; k += NTHREADS) {
        const int o = 4 * k;
        const int s = s_lo + o;
        f4v v;
        if (s >= 0 && s + 3 < NN) {
            v = __builtin_nontemporal_load((const f4v*)(xr + s));
        } else {
            #pragma unroll
            for (int j = 0; j < 4; ++j) {
                int ss = s + j;
                int idx = (ss < 0) ? (-ss - 1) : ((ss >= NN) ? (2 * NN - 1 - ss) : ss);
                v[j] = xr[idx];
            }
        }
        *(f4v*)&in_s[ldsidx(o)] = v;
    }
    __syncthreads();

    // ---- Phase 2+3: compute 4 outputs per quad, stage results ----
    const float LO[8] = {  0.23037781330885523f,  0.7148465705525415f,
                           0.6308807679295904f,  -0.02798376941698385f,
                          -0.18703481171888114f,  0.030841381835986965f,
                           0.032883011666982945f,-0.010597401784997278f };
    const float HI[8] = { -0.010597401784997278f,-0.032883011666982945f,
                           0.030841381835986965f, 0.18703481171888114f,
                          -0.02798376941698385f, -0.6308807679295904f,
                           0.7148465705525415f,  -0.23037781330885523f };

    for (int q = tid; 4 * q < touts; q += NTHREADS) {
        const int O = 8 * q;                 // output j uses v[2j+2 .. 2j+9]
        f4v a0 = *(const f4v*)&in_s[ldsidx(O)];
        f4v a1 = *(const f4v*)&in_s[ldsidx(O + 4)];
        f4v a2 = *(const f4v*)&in_s[ldsidx(O + 8)];
        f4v a3 = *(const f4v*)&in_s[ldsidx(O + 12)];
        float v[16] = { a0[0],a0[1],a0[2],a0[3], a1[0],a1[1],a1[2],a1[3],
                        a2[0],a2[1],a2[2],a2[3], a3[0],a3[1],a3[2],a3[3] };
        f4v accA, accD;
        #pragma unroll
        for (int j = 0; j < 4; ++j) {
            float a = 0.f, d = 0.f;
            #pragma unroll
            for (int m = 0; m < 8; ++m) {
                float vv = v[2 * j + 2 + m];
                a = fmaf(vv, LO[m], a);
                d = fmaf(vv, HI[m], d);
            }
            accA[j] = a; accD[j] = d;
        }
        *(f4v*)&cA_s[4 * q] = accA;
        *(f4v*)&cD_s[4 * q] = accD;
    }
    __syncthreads();

    // ---- Phase 4: LDS -> global, 16B-aligned non-temporal stores ----
    const size_t rb = (size_t)b * OUTROW;
    {   // cA stream; (g0 & 3) is even -> h in {0, 2}
        const size_t g0 = rb + t0;
        const int h = (int)((4 - (g0 & 3)) & 3);
        const int nv = (touts - h) >> 2;
        const int tail = touts - h - (nv << 2);
        if (tid < h) out[g0 + tid] = cA_s[tid];
        for (int k = tid; k < nv; k += NTHREADS) {
            const int lo = h + 4 * k;
            f2v p0 = *(const f2v*)&cA_s[lo];
            f2v p1 = *(const f2v*)&cA_s[lo + 2];
            f4v pv = { p0[0], p0[1], p1[0], p1[1] };
            __builtin_nontemporal_store(pv, (f4v*)(out + g0 + lo));
        }
        if (tid < tail) { const int lo = h + (nv << 2) + tid; out[g0 + lo] = cA_s[lo]; }
    }
    {   // cD stream; (g0 & 3) is odd -> h in {1, 3}
        const size_t g0 = rb + NOUT + t0;
        const int h = (int)((4 - (g0 & 3)) & 3);
        const int nv = (touts - h) >> 2;
        const int tail = touts - h - (nv << 2);
        if (tid < h) out[g0 + tid] = cD_s[tid];
        for (int k = tid; k < nv; k += NTHREADS) {
            const int lo = h + 4 * k;
            f4v pv = { cD_s[lo], cD_s[lo + 1], cD_s[lo + 2], cD_s[lo + 3] };
            __builtin_nontemporal_store(pv, (f4v*)(out + g0 + lo));
        }
        if (tid < tail) { const int lo = h + (nv << 2) + tid; out[g0 + lo] = cD_s[lo]; }
    }
}

extern "C" void kernel_launch(void* const* d_in, const int* in_sizes, int n_in,
                              void* d_out, int out_size, void* d_ws, size_t ws_size,
                              hipStream_t stream) {
    const float* x = (const float*)d_in[0];
    float* out = (float*)d_out;
    dim3 grid(GRIDX, BB);
    WaveletTransform_23244363006050_kernel<<<grid, dim3(NTHREADS), 0, stream>>>(x, out);
}